// Round 1
// baseline (264.729 us; speedup 1.0000x reference)
//
#include <hip/hip_runtime.h>

// CSConv2D: per-pixel kernel selection from a 25-entry 5x5 bank, depthwise
// (same kernel for all 96 channels at a spatial location), 'same' zero pad.
// B=8, C=96, H=W=192, fp32 in/out, buckets int32 (harness converts integer
// inputs to int32).
//
// Structure: block owns (batch b, row-tile of TH=4 rows, half the channels).
// Weights for the block's 768 pixels are gathered ONCE into 25 VGPRs/thread
// (weights are c-invariant), then a 48-iteration channel loop stages the
// (TH+4)-row input slab into double-buffered LDS (float2 loads, 1 barrier per
// iter) and each thread does 25 LDS-tap FMAs per output.

#define KS 5
#define NB 25
#define HALO 2
#define TH 4
#define WID 192
#define HEI 192
#define CH 96
#define NBATCH 8
#define LROW (WID + 2 * HALO)   // 196 floats per LDS row (2 zero-pad cols each side)
#define LH (TH + 2 * HALO)      // 8 staged rows
#define CSPLIT 2
#define CPB (CH / CSPLIT)       // 48 channels per block
#define NTHREADS (TH * WID)     // 768 threads = 12 waves

__global__ __launch_bounds__(NTHREADS, 6) void csconv_kernel(
    const float* __restrict__ in, const float* __restrict__ bank,
    const int* __restrict__ buckets, float* __restrict__ out)
{
    __shared__ float sb[NB * KS * KS];        // 625 floats: whole kernel bank
    __shared__ float sin_[2][LH][LROW];       // double-buffered input slab

    const int tid  = threadIdx.x;
    const int wcol = tid % WID;     // 0..191
    const int hl   = tid / WID;     // 0..TH-1
    const int cg   = blockIdx.x;    // channel group 0..CSPLIT-1
    const int ht   = blockIdx.y;    // row tile 0..47
    const int b    = blockIdx.z;    // batch 0..7
    const int h0   = ht * TH;
    const int h    = h0 + hl;

    // Stage kernel bank into LDS (2.5 KB, once per block).
    if (tid < NB * KS * KS) sb[tid] = bank[tid];
    // Zero the W-halo pad columns (cols 0,1,194,195) of both buffers once;
    // staging never overwrites them, so they persist across the c-loop.
    if (tid < 2 * LH * 4) {
        int buf = tid >> 5;         // 0..1
        int r   = (tid >> 2) & 7;   // 0..7
        int p   = tid & 3;          // 0..3
        int col = (p < 2) ? p : (WID + HALO + (p - 2));
        sin_[buf][r][col] = 0.0f;
    }
    __syncthreads();

    // Per-pixel weight gather: c-invariant, so done once per block.
    const int bkt = buckets[(b * HEI + h) * WID + wcol];
    float wreg[NB];
#pragma unroll
    for (int t = 0; t < NB; ++t) wreg[t] = sb[bkt * NB + t];

    const int c0 = cg * CPB;
    const float* inb  = in  + (size_t)(b * CH + c0) * (HEI * WID);
    float*       outb = out + (size_t)(b * CH + c0) * (HEI * WID);

    // Staging map: each thread loads one float2. 8 rows x 96 float2 = 768.
    const int srow = tid / (WID / 2);          // 0..7
    const int scol = (tid % (WID / 2)) * 2;    // even column
    const int hg   = h0 - HALO + srow;         // global input row (may be OOB)
    const bool row_ok = (hg >= 0) && (hg < HEI);
    const float* src_base = inb + (size_t)hg * WID + scol;  // valid only if row_ok

    // Prologue: stage c=0 into buffer 0.
    {
        float2 v = make_float2(0.0f, 0.0f);
        if (row_ok) v = *(const float2*)src_base;
        *(float2*)&sin_[0][srow][scol + HALO] = v;
    }
    __syncthreads();

#pragma unroll 2
    for (int c = 0; c < CPB; ++c) {
        const int cur = c & 1;
        // Stage next channel into the other buffer. Safe: that buffer's
        // readers (iteration c-1) finished before the barrier ending c-1.
        if (c + 1 < CPB) {
            float2 v = make_float2(0.0f, 0.0f);
            if (row_ok) v = *(const float2*)(src_base + (size_t)(c + 1) * (HEI * WID));
            *(float2*)&sin_[cur ^ 1][srow][scol + HALO] = v;
        }
        // 25-tap conv from LDS; 5 partial accumulators to break the FMA chain.
        float acc = 0.0f;
#pragma unroll
        for (int i = 0; i < KS; ++i) {
            float s = 0.0f;
#pragma unroll
            for (int j = 0; j < KS; ++j)
                s += sin_[cur][hl + i][wcol + j] * wreg[i * KS + j];
            acc += s;
        }
        outb[((size_t)c * HEI + h) * WID + wcol] = acc;
        __syncthreads();
    }
}

extern "C" void kernel_launch(void* const* d_in, const int* in_sizes, int n_in,
                              void* d_out, int out_size, void* d_ws, size_t ws_size,
                              hipStream_t stream) {
    const float* in      = (const float*)d_in[0];
    const float* bank    = (const float*)d_in[1];
    const int*   buckets = (const int*)d_in[2];
    float*       out     = (float*)d_out;
    dim3 grid(CSPLIT, HEI / TH, NBATCH);
    csconv_kernel<<<grid, NTHREADS, 0, stream>>>(in, bank, buckets, out);
}

// Round 3
// 237.878 us; speedup vs baseline: 1.1129x; 1.1129x over previous
//
#include <hip/hip_runtime.h>

// CSConv2D: per-pixel kernel selection from a 25-entry 5x5 bank, depthwise,
// 'same' zero pad. B=8, C=96, H=W=192, fp32.
//
// R2 structure: vertical register blocking. Each thread computes 4 output
// rows of one column; each staged input row-segment (5 floats) feeds up to 4
// accumulators, so LDS tap-reads drop from 25/output to 10/output. Weights
// for the 4 rows (4 buckets) live in ~100 VGPRs, gathered once per block
// (channel-invariant). R1 was LDS-pipe bound (VALU 27%, HBM 22%, 0 bank
// conflicts, 128us vs 36us HBM floor).
//
// R3 fix: bank staging must be grid-stride — 625 bank elements > 384 threads
// (R2 left sb[384..624] poisoned -> absmax 64).

#define KS 5
#define NB 25
#define HALO 2
#define TH 8                    // output rows per block
#define RPT 4                   // output rows per thread
#define WID 192
#define HEI 192
#define CH 96
#define NBATCH 8
#define LROW (WID + 2 * HALO)   // 196 floats per LDS row
#define LH (TH + 2 * HALO)      // 12 staged rows
#define CSPLIT 4
#define CPB (CH / CSPLIT)       // 24 channels per block
#define NTHREADS (WID * (TH / RPT))  // 384 threads = 6 waves
#define SLOTS_PER_THREAD 3      // 12 rows * 96 float2 slots / 384 threads

__global__ __launch_bounds__(NTHREADS, 3) void csconv_kernel(
    const float* __restrict__ in, const float* __restrict__ bank,
    const int* __restrict__ buckets, float* __restrict__ out)
{
    __shared__ float sb[NB * KS * KS];        // 625 floats: whole kernel bank
    __shared__ float sin_[2][LH][LROW];       // double-buffered input slab

    const int tid  = threadIdx.x;
    const int wcol = tid % WID;     // 0..191
    const int ty   = tid / WID;     // 0..1 (thread-row group)
    const int cg   = blockIdx.x;    // channel group 0..3
    const int ht   = blockIdx.y;    // row tile 0..23
    const int b    = blockIdx.z;    // batch 0..7
    const int h0   = ht * TH;
    const int r0   = h0 + ty * RPT; // first output row this thread owns

    // Stage kernel bank into LDS (2.5 KB, once per block). 625 > NTHREADS,
    // so this MUST be a strided loop.
    for (int t = tid; t < NB * KS * KS; t += NTHREADS) sb[t] = bank[t];
    // Zero the W-halo pad columns (0,1,194,195) of both buffers once; the
    // channel staging only writes cols 2..193, so the pad persists.
    if (tid < 2 * LH * 4) {
        int buf = tid / (LH * 4);
        int r   = (tid / 4) % LH;
        int p   = tid & 3;
        int col = (p < 2) ? p : (WID + HALO + (p - 2));
        sin_[buf][r][col] = 0.0f;
    }
    __syncthreads();

    // Per-pixel weight gather: channel-invariant, once per block. 4 rows =>
    // 4 buckets => 100 weight registers per thread.
    float wreg[RPT][NB];
#pragma unroll
    for (int r = 0; r < RPT; ++r) {
        const int bkt = buckets[(b * HEI + r0 + r) * WID + wcol];
#pragma unroll
        for (int t = 0; t < NB; ++t) wreg[r][t] = sb[bkt * NB + t];
    }

    const int c0 = cg * CPB;
    const float* inb  = in  + (size_t)(b * CH + c0) * (HEI * WID);
    float*       outb = out + (size_t)(b * CH + c0) * (HEI * WID);

    // Staging map: 12 rows x 96 float2 = 1152 slots; thread t owns slots
    // t, t+384, t+768 -> same column pair, staged rows (t/96) + {0,4,8}.
    const int srow0 = tid / (WID / 2);         // 0..3
    const int scol  = (tid % (WID / 2)) * 2;   // even column 0..190
    bool row_ok[SLOTS_PER_THREAD];
    const float* srcp[SLOTS_PER_THREAD];
#pragma unroll
    for (int k = 0; k < SLOTS_PER_THREAD; ++k) {
        const int srow = srow0 + 4 * k;
        const int hg   = h0 - HALO + srow;
        row_ok[k] = (hg >= 0) && (hg < HEI);
        srcp[k]   = inb + (size_t)hg * WID + scol;   // deref only if row_ok
    }

    // Prologue: stage c=0 into buffer 0.
#pragma unroll
    for (int k = 0; k < SLOTS_PER_THREAD; ++k) {
        float2 v = make_float2(0.0f, 0.0f);
        if (row_ok[k]) v = *(const float2*)srcp[k];
        *(float2*)&sin_[0][srow0 + 4 * k][scol + HALO] = v;
    }
    __syncthreads();

    const int ty4 = ty * RPT;
    for (int c = 0; c < CPB; ++c) {
        const int cur = c & 1;
        // Issue next channel's staging loads early; consume (ds_write) after
        // the conv so the VMEM latency is covered by compute.
        float2 v[SLOTS_PER_THREAD];
        const bool has_next = (c + 1 < CPB);
        if (has_next) {
            const size_t coff = (size_t)(c + 1) * (HEI * WID);
#pragma unroll
            for (int k = 0; k < SLOTS_PER_THREAD; ++k) {
                v[k] = make_float2(0.0f, 0.0f);
                if (row_ok[k]) v[k] = *(const float2*)(srcp[k] + coff);
            }
        }

        // Conv: 8 staged rows feed 4 vertically-adjacent outputs.
        float acc[RPT] = {0.0f, 0.0f, 0.0f, 0.0f};
#pragma unroll
        for (int i = 0; i < TH; ++i) {
            const float* rowp = &sin_[cur][ty4 + i][wcol];
            const float x0 = rowp[0], x1 = rowp[1], x2 = rowp[2],
                        x3 = rowp[3], x4 = rowp[4];
#pragma unroll
            for (int r = 0; r < RPT; ++r) {
                const int ki = i - r;
                if (ki >= 0 && ki < KS) {   // compile-time after unroll
                    const float* w = &wreg[r][ki * KS];
                    acc[r] += x0 * w[0] + x1 * w[1] + x2 * w[2]
                            + x3 * w[3] + x4 * w[4];
                }
            }
        }

        if (has_next) {
#pragma unroll
            for (int k = 0; k < SLOTS_PER_THREAD; ++k)
                *(float2*)&sin_[cur ^ 1][srow0 + 4 * k][scol + HALO] = v[k];
        }

#pragma unroll
        for (int r = 0; r < RPT; ++r)
            outb[((size_t)c * HEI + r0 + r) * WID + wcol] = acc[r];

        __syncthreads();
    }
}

extern "C" void kernel_launch(void* const* d_in, const int* in_sizes, int n_in,
                              void* d_out, int out_size, void* d_ws, size_t ws_size,
                              hipStream_t stream) {
    const float* in      = (const float*)d_in[0];
    const float* bank    = (const float*)d_in[1];
    const int*   buckets = (const int*)d_in[2];
    float*       out     = (float*)d_out;
    dim3 grid(CSPLIT, HEI / TH, NBATCH);
    csconv_kernel<<<grid, NTHREADS, 0, stream>>>(in, bank, buckets, out);
}